// Round 1
// baseline (1685.574 us; speedup 1.0000x reference)
//
#include <hip/hip_runtime.h>

#define TPB 256

__device__ __forceinline__ void fma4(float4& a, float s, float4 b){
  a.x = fmaf(s,b.x,a.x); a.y = fmaf(s,b.y,a.y);
  a.z = fmaf(s,b.z,a.z); a.w = fmaf(s,b.w,a.w);
}

__device__ __forceinline__ int vox(int b,int z,int y,int x,int ld){
  return ((((((b<<ld)|z)<<ld)|y)<<ld)|x);
}

__global__ __launch_bounds__(TPB) void k_zero(float* __restrict__ p, int n){
  int i = blockIdx.x*blockDim.x + threadIdx.x;
  if(i<n) p[i]=0.f;
}

__global__ __launch_bounds__(TPB) void k_scatter(const float* __restrict__ data, const int* __restrict__ cl,
                                                 int n, float* __restrict__ c0){
  int i = blockIdx.x*blockDim.x + threadIdx.x;
  if(i>=n) return;
  int z = (int)data[i*5+0];
  int y = (int)data[i*5+1];
  int x = (int)data[i*5+2];
  int b = cl[i];
  atomicAdd(&c0[vox(b,z,y,x,6)], 1.0f);
}

__global__ __launch_bounds__(TPB) void k_mask(const float* __restrict__ c0, float* __restrict__ m0, int n){
  int i = blockIdx.x*blockDim.x + threadIdx.x;
  if(i<n) m0[i] = (c0[i]>0.f) ? 1.f : 0.f;
}

// prepare: 1 -> 16 channels, k=3 SAME, input = count grid, masked
__global__ __launch_bounds__(TPB) void k_prep(const float* __restrict__ c0, const float* __restrict__ m0,
                                              const float* __restrict__ w, float* __restrict__ X){
  __shared__ float wl[432];
  for(int i=threadIdx.x;i<432;i+=TPB) wl[i]=w[i];
  __syncthreads();
  int v = blockIdx.x*blockDim.x + threadIdx.x;
  if(v >= (4<<18)) return;
  float4 a0=make_float4(0,0,0,0), a1=a0, a2=a0, a3=a0;
  if(m0[v]!=0.f){
    int x=v&63, y=(v>>6)&63, z=(v>>12)&63, b=v>>18;
    for(int dz=0;dz<3;dz++){ int zz=z+dz-1; if((unsigned)zz>=64u) continue;
      for(int dy=0;dy<3;dy++){ int yy=y+dy-1; if((unsigned)yy>=64u) continue;
        for(int dx=0;dx<3;dx++){ int xx=x+dx-1; if((unsigned)xx>=64u) continue;
          float av = c0[vox(b,zz,yy,xx,6)];
          if(av==0.f) continue;
          const float4* wv = (const float4*)&wl[((dz*3+dy)*3+dx)<<4];
          fma4(a0,av,wv[0]); fma4(a1,av,wv[1]); fma4(a2,av,wv[2]); fma4(a3,av,wv[3]);
        }
      }
    }
  }
  float4* o = (float4*)(X + ((size_t)v<<4));
  o[0]=a0; o[1]=a1; o[2]=a2; o[3]=a3;
}

// generic 16->16 k=3 SAME conv, output masked
__global__ __launch_bounds__(TPB) void k_conv3(const float* __restrict__ Xin, const float* __restrict__ m,
      const float* __restrict__ w, float* __restrict__ Xout, int ld, int nvox){
  __shared__ float wl[6912];
  for(int i=threadIdx.x;i<6912;i+=TPB) wl[i]=w[i];
  __syncthreads();
  int v = blockIdx.x*blockDim.x + threadIdx.x;
  if(v>=nvox) return;
  int d=1<<ld, dm=d-1;
  float4 a0=make_float4(0,0,0,0), a1=a0, a2=a0, a3=a0;
  if(m[v]!=0.f){
    int x=v&dm, y=(v>>ld)&dm, z=(v>>(2*ld))&dm, b=v>>(3*ld);
    for(int dz=0;dz<3;dz++){ int zz=z+dz-1; if((unsigned)zz>=(unsigned)d) continue;
      for(int dy=0;dy<3;dy++){ int yy=y+dy-1; if((unsigned)yy>=(unsigned)d) continue;
        const float* srow = Xin + ((size_t)vox(b,zz,yy,0,ld)<<4);
        const float* wrow = &wl[((dz*3+dy)*3)<<8];
        for(int dx=0;dx<3;dx++){ int xx=x+dx-1; if((unsigned)xx>=(unsigned)d) continue;
          const float4* sp = (const float4*)(srow + ((size_t)xx<<4));
          float s[16];
          *(float4*)&s[0]=sp[0]; *(float4*)&s[4]=sp[1]; *(float4*)&s[8]=sp[2]; *(float4*)&s[12]=sp[3];
          const float* wt = wrow + (dx<<8);
          #pragma unroll
          for(int ci=0;ci<16;ci++){
            float av=s[ci];
            const float4* wv=(const float4*)(wt + (ci<<4));
            fma4(a0,av,wv[0]); fma4(a1,av,wv[1]); fma4(a2,av,wv[2]); fma4(a3,av,wv[3]);
          }
        }
      }
    }
  }
  float4* o=(float4*)(Xout + ((size_t)v<<4));
  o[0]=a0;o[1]=a1;o[2]=a2;o[3]=a3;
}

// k=4, pad (1,2): out[o] = sum_{t=0..3} in[o+t-1] * w[t]
__global__ __launch_bounds__(TPB) void k_conv4(const float* __restrict__ Xin, const float* __restrict__ m,
      const float* __restrict__ w, float* __restrict__ Xout, int ld, int nvox){
  extern __shared__ float wl4[];
  for(int i=threadIdx.x;i<16384;i+=TPB) wl4[i]=w[i];
  __syncthreads();
  int v = blockIdx.x*blockDim.x + threadIdx.x;
  if(v>=nvox) return;
  int d=1<<ld, dm=d-1;
  float4 a0=make_float4(0,0,0,0), a1=a0, a2=a0, a3=a0;
  if(m[v]!=0.f){
    int x=v&dm, y=(v>>ld)&dm, z=(v>>(2*ld))&dm, b=v>>(3*ld);
    for(int dz=0;dz<4;dz++){ int zz=z+dz-1; if((unsigned)zz>=(unsigned)d) continue;
      for(int dy=0;dy<4;dy++){ int yy=y+dy-1; if((unsigned)yy>=(unsigned)d) continue;
        const float* srow = Xin + ((size_t)vox(b,zz,yy,0,ld)<<4);
        const float* wrow = &wl4[((dz*4+dy))<<10];
        for(int dx=0;dx<4;dx++){ int xx=x+dx-1; if((unsigned)xx>=(unsigned)d) continue;
          const float4* sp = (const float4*)(srow + ((size_t)xx<<4));
          float s[16];
          *(float4*)&s[0]=sp[0]; *(float4*)&s[4]=sp[1]; *(float4*)&s[8]=sp[2]; *(float4*)&s[12]=sp[3];
          const float* wt = wrow + (dx<<8);
          #pragma unroll
          for(int ci=0;ci<16;ci++){
            float av=s[ci];
            const float4* wv=(const float4*)(wt + (ci<<4));
            fma4(a0,av,wv[0]); fma4(a1,av,wv[1]); fma4(a2,av,wv[2]); fma4(a3,av,wv[3]);
          }
        }
      }
    }
  }
  float4* o=(float4*)(Xout + ((size_t)v<<4));
  o[0]=a0;o[1]=a1;o[2]=a2;o[3]=a3;
}

__global__ __launch_bounds__(TPB) void k_downmask(const float* __restrict__ mf, float* __restrict__ mc,
                                                  int ldc, int nc){
  int v = blockIdx.x*blockDim.x + threadIdx.x;
  if(v>=nc) return;
  int dm=(1<<ldc)-1, ldf=ldc+1;
  int x=v&dm, y=(v>>ldc)&dm, z=(v>>(2*ldc))&dm, b=v>>(3*ldc);
  float mm=0.f;
  for(int dz=0;dz<2;dz++) for(int dy=0;dy<2;dy++) for(int dx=0;dx<2;dx++)
    mm = fmaxf(mm, mf[vox(b,2*z+dz,2*y+dy,2*x+dx,ldf)]);
  mc[v]=mm;
}

// strided k=2 s=2 VALID down-conv, output masked by coarse mask
__global__ __launch_bounds__(TPB) void k_down(const float* __restrict__ Xin, const float* __restrict__ mc,
      const float* __restrict__ w, float* __restrict__ Xout, int ldc, int nc){
  __shared__ float wl[2048];
  for(int i=threadIdx.x;i<2048;i+=TPB) wl[i]=w[i];
  __syncthreads();
  int v = blockIdx.x*blockDim.x + threadIdx.x;
  if(v>=nc) return;
  int dm=(1<<ldc)-1, ldf=ldc+1;
  float4 a0=make_float4(0,0,0,0), a1=a0, a2=a0, a3=a0;
  if(mc[v]!=0.f){
    int x=v&dm, y=(v>>ldc)&dm, z=(v>>(2*ldc))&dm, b=v>>(3*ldc);
    for(int dz=0;dz<2;dz++) for(int dy=0;dy<2;dy++) for(int dx=0;dx<2;dx++){
      const float4* sp=(const float4*)(Xin + ((size_t)vox(b,2*z+dz,2*y+dy,2*x+dx,ldf)<<4));
      float s[16];
      *(float4*)&s[0]=sp[0]; *(float4*)&s[4]=sp[1]; *(float4*)&s[8]=sp[2]; *(float4*)&s[12]=sp[3];
      const float* wt=&wl[(((dz<<1)|dy)<<1 | dx)<<8];
      #pragma unroll
      for(int ci=0;ci<16;ci++){
        float av=s[ci];
        const float4* wv=(const float4*)(wt+(ci<<4));
        fma4(a0,av,wv[0]); fma4(a1,av,wv[1]); fma4(a2,av,wv[2]); fma4(a3,av,wv[3]);
      }
    }
  }
  float4* o=(float4*)(Xout+((size_t)v<<4));
  o[0]=a0;o[1]=a1;o[2]=a2;o[3]=a3;
}

// conv_transpose k=2 s=2 VALID: out[2i+di] uses w[1-di,1-dj,1-dk,ci,co]; masked by fine mask
__global__ __launch_bounds__(TPB) void k_up(const float* __restrict__ Xc, const float* __restrict__ mf,
      const float* __restrict__ w, float* __restrict__ Xf, int ldf, int nf){
  __shared__ float wl[2048];
  for(int i=threadIdx.x;i<2048;i+=TPB) wl[i]=w[i];
  __syncthreads();
  int v = blockIdx.x*blockDim.x + threadIdx.x;
  if(v>=nf) return;
  int dm=(1<<ldf)-1, ldc=ldf-1;
  float4 a0=make_float4(0,0,0,0), a1=a0, a2=a0, a3=a0;
  if(mf[v]!=0.f){
    int x=v&dm, y=(v>>ldf)&dm, z=(v>>(2*ldf))&dm, b=v>>(3*ldf);
    const float4* sp=(const float4*)(Xc + ((size_t)vox(b,z>>1,y>>1,x>>1,ldc)<<4));
    float s[16];
    *(float4*)&s[0]=sp[0]; *(float4*)&s[4]=sp[1]; *(float4*)&s[8]=sp[2]; *(float4*)&s[12]=sp[3];
    int t = ((((z&1)^1)<<1 | ((y&1)^1))<<1) | ((x&1)^1);
    const float* wt=&wl[t<<8];
    #pragma unroll
    for(int ci=0;ci<16;ci++){
      float av=s[ci];
      const float4* wv=(const float4*)(wt+(ci<<4));
      fma4(a0,av,wv[0]); fma4(a1,av,wv[1]); fma4(a2,av,wv[2]); fma4(a3,av,wv[3]);
    }
  }
  float4* o=(float4*)(Xf+((size_t)v<<4));
  o[0]=a0;o[1]=a1;o[2]=a2;o[3]=a3;
}

// masked BN statistics: stats[0..15]=sum, [16..31]=sumsq, [32]=count
__global__ __launch_bounds__(TPB) void k_bnstats(const float* __restrict__ X, const float* __restrict__ m,
                                                 int nvox, float* __restrict__ stats){
  float ls[16], lss[16];
  #pragma unroll
  for(int c=0;c<16;c++){ ls[c]=0.f; lss[c]=0.f; }
  float ln=0.f;
  for(int v = blockIdx.x*blockDim.x+threadIdx.x; v<nvox; v+=gridDim.x*blockDim.x){
    if(m[v]!=0.f){
      ln += 1.f;
      const float* p = X + ((size_t)v<<4);
      #pragma unroll
      for(int c=0;c<16;c++){ float a=p[c]; ls[c]+=a; lss[c]=fmaf(a,a,lss[c]); }
    }
  }
  #pragma unroll
  for(int c=0;c<16;c++){
    for(int o=32;o>0;o>>=1){ ls[c]+=__shfl_down(ls[c],o,64); lss[c]+=__shfl_down(lss[c],o,64); }
  }
  for(int o=32;o>0;o>>=1) ln+=__shfl_down(ln,o,64);
  __shared__ float sred[4*33];
  int wv = threadIdx.x>>6, lane = threadIdx.x&63;
  if(lane==0){
    #pragma unroll
    for(int c=0;c<16;c++){ sred[wv*33+c]=ls[c]; sred[wv*33+16+c]=lss[c]; }
    sred[wv*33+32]=ln;
  }
  __syncthreads();
  if(threadIdx.x<33){
    float t=0.f;
    for(int w2=0;w2<4;w2++) t+=sred[w2*33+threadIdx.x];
    atomicAdd(&stats[threadIdx.x], t);
  }
}

// fold stats+gamma/beta into per-channel scale/shift: stats[33..48]=scale, [49..64]=shift
__global__ void k_bnfin(float* __restrict__ stats, const float* __restrict__ g, const float* __restrict__ bta){
  int c = threadIdx.x;
  if(c>=16) return;
  float n = stats[32]; if(n<1.f) n=1.f;
  float mean = stats[c]/n;
  float var = stats[16+c]/n - mean*mean;
  float sc = g[c]/sqrtf(var+1e-4f);
  stats[33+c]=sc;
  stats[49+c]=fmaf(-mean,sc,bta[c]);
}

// apply BN + ReLU (LEAK=0) + mask, in place
__global__ __launch_bounds__(TPB) void k_bnapply(float* __restrict__ X, const float* __restrict__ m,
                                                 const float* __restrict__ stats, int nvox){
  int v = blockIdx.x*blockDim.x + threadIdx.x;
  if(v>=nvox) return;
  float* p = X + ((size_t)v<<4);
  if(m[v]==0.f){
    float4 zz=make_float4(0,0,0,0);
    float4* o=(float4*)p; o[0]=zz;o[1]=zz;o[2]=zz;o[3]=zz;
    return;
  }
  #pragma unroll
  for(int c=0;c<16;c++){
    float xh = fmaf(p[c], stats[33+c], stats[49+c]);
    p[c] = xh>0.f ? xh : 0.f;
  }
}

// mask = mask * (x[ch0] > 0); x *= mask  (in place)
__global__ __launch_bounds__(TPB) void k_sparsify(float* __restrict__ X, float* __restrict__ m, int nvox){
  int v = blockIdx.x*blockDim.x + threadIdx.x;
  if(v>=nvox) return;
  bool a = (m[v]!=0.f) && (X[(size_t)v<<4] > 0.f);
  m[v] = a ? 1.f : 0.f;
  if(!a){
    float4 zz=make_float4(0,0,0,0);
    float4* o=(float4*)(X+((size_t)v<<4)); o[0]=zz;o[1]=zz;o[2]=zz;o[3]=zz;
  }
}

// hidden = NCDHW flatten of level-3 features: out[b*8192 + c*512 + s] = X3[(b*512+s)*16+c]
__global__ __launch_bounds__(TPB) void k_hidden(const float* __restrict__ X3, float* __restrict__ out){
  int i = blockIdx.x*blockDim.x + threadIdx.x;
  if(i>=4*8192) return;
  int b=i>>13, r=i&8191, c=r>>9, s=r&511;
  out[i] = X3[(((size_t)((b<<9)|s))<<4)|c];
}

// output conv 16 -> 1, k=3 SAME, masked
__global__ __launch_bounds__(TPB) void k_final(const float* __restrict__ Xin, const float* __restrict__ m,
      const float* __restrict__ w, float* __restrict__ out){
  __shared__ float wl[432];
  for(int i=threadIdx.x;i<432;i+=TPB) wl[i]=w[i];
  __syncthreads();
  int v = blockIdx.x*blockDim.x + threadIdx.x;
  if(v>=(4<<18)) return;
  float acc=0.f;
  if(m[v]!=0.f){
    int x=v&63, y=(v>>6)&63, z=(v>>12)&63, b=v>>18;
    for(int dz=0;dz<3;dz++){ int zz=z+dz-1; if((unsigned)zz>=64u) continue;
      for(int dy=0;dy<3;dy++){ int yy=y+dy-1; if((unsigned)yy>=64u) continue;
        for(int dx=0;dx<3;dx++){ int xx=x+dx-1; if((unsigned)xx>=64u) continue;
          const float* sp = Xin + ((size_t)vox(b,zz,yy,xx,6)<<4);
          const float* wt = &wl[((dz*3+dy)*3+dx)<<4];
          #pragma unroll
          for(int ci=0;ci<16;ci++) acc = fmaf(sp[ci], wt[ci], acc);
        }
      }
    }
  }
  out[v]=acc;
}

static inline int nb(int n){ return (n+TPB-1)/TPB; }

extern "C" void kernel_launch(void* const* d_in, const int* in_sizes, int n_in,
                              void* d_out, int out_size, void* d_ws, size_t ws_size,
                              hipStream_t stream){
  const float* data   = (const float*)d_in[0];
  const int*   cl     = (const int*)d_in[1];
  const float* w_prep = (const float*)d_in[2];
  const float* enc_g  = (const float*)d_in[3];
  const float* enc_b  = (const float*)d_in[4];
  const float* enc_ws = (const float*)d_in[5];
  const float* enc_wd = (const float*)d_in[6];
  const float* dec_g  = (const float*)d_in[7];
  const float* dec_b  = (const float*)d_in[8];
  const float* dec_wu = (const float*)d_in[9];
  const float* dec_w3 = (const float*)d_in[10];
  const float* dec_w4 = (const float*)d_in[11];
  const float* w_out  = (const float*)d_in[12];
  int N = in_sizes[0]/5;

  float* ws = (float*)d_ws;
  float* X  = ws;                       // 16,777,216 floats (L0 feature ping)
  float* Y  = X + (size_t)(4<<18)*16;   // 16,777,216 floats (pong)
  float* c0 = Y + (size_t)(4<<18)*16;   // 1,048,576 (count grid)
  float* m0 = c0 + (4<<18);             // 1,048,576
  float* m1 = m0 + (4<<18);             // 131,072
  float* m2 = m1 + (4<<15);             // 16,384
  float* m3 = m2 + (4<<12);             // 2,048
  float* stats = m3 + (4<<9);           // 66
  float* masks[4] = {m0,m1,m2,m3};
  float* out = (float*)d_out;

  const int n0 = 4<<18;

  k_zero<<<nb(n0),TPB,0,stream>>>(c0, n0);
  k_scatter<<<nb(N),TPB,0,stream>>>(data, cl, N, c0);
  k_mask<<<nb(n0),TPB,0,stream>>>(c0, m0, n0);
  k_prep<<<nb(n0),TPB,0,stream>>>(c0, m0, w_prep, X);

  float* cur=X; float* oth=Y;
  int ld=6;
  // encoder
  for(int i=0;i<3;i++){
    int nv = 4<<(3*ld);
    int sblk = nb(nv); if(sblk>768) sblk=768;
    k_zero<<<1,64,0,stream>>>(stats,33);
    k_bnstats<<<sblk,TPB,0,stream>>>(cur, masks[i], nv, stats);
    k_bnfin<<<1,64,0,stream>>>(stats, enc_g+i*16, enc_b+i*16);
    k_bnapply<<<nb(nv),TPB,0,stream>>>(cur, masks[i], stats, nv);
    k_conv3<<<nb(nv),TPB,0,stream>>>(cur, masks[i], enc_ws+i*6912, oth, ld, nv);
    { float* t=cur; cur=oth; oth=t; }
    int ldc=ld-1; int nc = 4<<(3*ldc);
    k_downmask<<<nb(nc),TPB,0,stream>>>(masks[i], masks[i+1], ldc, nc);
    k_down<<<nb(nc),TPB,0,stream>>>(cur, masks[i+1], enc_wd+i*2048, oth, ldc, nc);
    { float* t=cur; cur=oth; oth=t; }
    ld=ldc;
  }
  // hidden (level 3, before decoder BN)
  k_hidden<<<nb(4*8192),TPB,0,stream>>>(cur, out);
  // decoder
  for(int j=0;j<3;j++){
    int lvl=2-j;
    int nv = 4<<(3*ld);
    int sblk = nb(nv); if(sblk>768) sblk=768;
    k_zero<<<1,64,0,stream>>>(stats,33);
    k_bnstats<<<sblk,TPB,0,stream>>>(cur, masks[lvl+1], nv, stats);
    k_bnfin<<<1,64,0,stream>>>(stats, dec_g+j*16, dec_b+j*16);
    k_bnapply<<<nb(nv),TPB,0,stream>>>(cur, masks[lvl+1], stats, nv);
    int ldf=ld+1; int nf = 4<<(3*ldf);
    k_up<<<nb(nf),TPB,0,stream>>>(cur, masks[lvl], dec_wu+j*2048, oth, ldf, nf);
    { float* t=cur; cur=oth; oth=t; }
    k_conv3<<<nb(nf),TPB,0,stream>>>(cur, masks[lvl], dec_w3+j*6912, oth, ldf, nf);
    { float* t=cur; cur=oth; oth=t; }
    k_sparsify<<<nb(nf),TPB,0,stream>>>(cur, masks[lvl], nf);
    k_conv4<<<nb(nf),TPB,65536,stream>>>(cur, masks[lvl], dec_w4+j*16384, oth, ldf, nf);
    { float* t=cur; cur=oth; oth=t; }
    ld=ldf;
  }
  k_final<<<nb(n0),TPB,0,stream>>>(cur, masks[0], w_out, out+32768);
}

// Round 2
// 1140.682 us; speedup vs baseline: 1.4777x; 1.4777x over previous
//
#include <hip/hip_runtime.h>

#define TPB 256
#define CTPB 512

__device__ __forceinline__ void fma4(float4& a, float s, const float4 b){
  a.x = fmaf(s,b.x,a.x); a.y = fmaf(s,b.y,a.y);
  a.z = fmaf(s,b.z,a.z); a.w = fmaf(s,b.w,a.w);
}

__device__ __forceinline__ int vox(int b,int z,int y,int x,int ld){
  return ((((((b<<ld)|z)<<ld)|y)<<ld)|x);
}

__global__ __launch_bounds__(TPB) void k_scatter(const float* __restrict__ data, const int* __restrict__ cl,
                                                 int n, float* __restrict__ c0){
  int i = blockIdx.x*blockDim.x + threadIdx.x;
  if(i>=n) return;
  int z = (int)data[i*5+0];
  int y = (int)data[i*5+1];
  int x = (int)data[i*5+2];
  atomicAdd(&c0[vox(cl[i],z,y,x,6)], 1.0f);
}

// mask + ballot-compaction of occupied voxels from count grid
__global__ __launch_bounds__(TPB) void k_compact0(const float* __restrict__ c0, float* __restrict__ m0,
                                                  int n, int* __restrict__ list, int* __restrict__ cnt){
  int i = blockIdx.x*blockDim.x + threadIdx.x;
  if(i>=n) return;
  bool a = c0[i] > 0.f;
  m0[i] = a ? 1.f : 0.f;
  unsigned long long b = __ballot(a);
  int lane = threadIdx.x & 63;
  int base = 0;
  if(lane==0){ int pop = __popcll(b); if(pop) base = atomicAdd(cnt, pop); }
  base = __shfl(base, 0, 64);
  if(a) list[base + __popcll(b & ((1ull<<lane)-1ull))] = i;
}

// coarse mask = max over 2x2x2 fine window, plus compaction of active coarse voxels
__global__ __launch_bounds__(TPB) void k_downmask_compact(const float* __restrict__ mf, float* __restrict__ mc,
                        int ldc, int nc, int* __restrict__ list, int* __restrict__ cnt){
  int v = blockIdx.x*blockDim.x + threadIdx.x;
  if(v>=nc) return;
  int dm=(1<<ldc)-1, ldf=ldc+1;
  int x=v&dm, y=(v>>ldc)&dm, z=(v>>(2*ldc))&dm, b=v>>(3*ldc);
  float mm=0.f;
  for(int dz=0;dz<2;dz++) for(int dy=0;dy<2;dy++) for(int dx=0;dx<2;dx++)
    mm = fmaxf(mm, mf[vox(b,2*z+dz,2*y+dy,2*x+dx,ldf)]);
  mc[v]=mm;
  bool a = mm>0.f;
  unsigned long long bl = __ballot(a);
  int lane = threadIdx.x & 63;
  int base = 0;
  if(lane==0){ int pop = __popcll(bl); if(pop) base = atomicAdd(cnt, pop); }
  base = __shfl(base, 0, 64);
  if(a) list[base + __popcll(bl & ((1ull<<lane)-1ull))] = v;
}

// sparsify: keep sites with ch0 > 0; zero dropped sites' features in BOTH buffers; compact keepers
__global__ __launch_bounds__(TPB) void k_sparsify_compact(float* __restrict__ X, float* __restrict__ Y,
        const int* __restrict__ listA, const int* __restrict__ cntA,
        int* __restrict__ listB, int* __restrict__ cntB){
  int i = blockIdx.x*blockDim.x + threadIdx.x;
  if(i >= *cntA) return;
  int v = listA[i];
  bool keep = X[(size_t)v<<4] > 0.f;
  if(!keep){
    float4 zz = make_float4(0,0,0,0);
    float4* px=(float4*)(X+((size_t)v<<4)); px[0]=zz;px[1]=zz;px[2]=zz;px[3]=zz;
    float4* py=(float4*)(Y+((size_t)v<<4)); py[0]=zz;py[1]=zz;py[2]=zz;py[3]=zz;
  }
  unsigned long long bl = __ballot(keep);
  int lane = threadIdx.x & 63;
  int base = 0;
  if(lane==0){ int pop = __popcll(bl); if(pop) base = atomicAdd(cntB, pop); }
  base = __shfl(base, 0, 64);
  if(keep) listB[base + __popcll(bl & ((1ull<<lane)-1ull))] = v;
}

// prepare: 1 -> 16 channels, k=3 SAME, over active list
__global__ __launch_bounds__(TPB) void k_prep_l(const float* __restrict__ c0, const int* __restrict__ list,
          const int* __restrict__ cnt, const float* __restrict__ w, float* __restrict__ X){
  __shared__ float wl[432];
  for(int i=threadIdx.x;i<432;i+=TPB) wl[i]=w[i];
  __syncthreads();
  int i = blockIdx.x*blockDim.x + threadIdx.x;
  if(i >= *cnt) return;
  int v = list[i];
  int x=v&63, y=(v>>6)&63, z=(v>>12)&63, b=v>>18;
  float4 a0=make_float4(0,0,0,0), a1=a0, a2=a0, a3=a0;
  for(int dz=0;dz<3;dz++){ int zz=z+dz-1; if((unsigned)zz>=64u) continue;
    for(int dy=0;dy<3;dy++){ int yy=y+dy-1; if((unsigned)yy>=64u) continue;
      for(int dx=0;dx<3;dx++){ int xx=x+dx-1; if((unsigned)xx>=64u) continue;
        float av = c0[vox(b,zz,yy,xx,6)];
        if(av==0.f) continue;
        const float4* wv = (const float4*)&wl[((dz*3+dy)*3+dx)<<4];
        fma4(a0,av,wv[0]); fma4(a1,av,wv[1]); fma4(a2,av,wv[2]); fma4(a3,av,wv[3]);
      }
    }
  }
  float4* o = (float4*)(X + ((size_t)v<<4));
  o[0]=a0; o[1]=a1; o[2]=a2; o[3]=a3;
}

// 16->16 k=3 SAME conv over active list
__global__ __launch_bounds__(CTPB) void k_conv3_l(const float* __restrict__ Xin, const int* __restrict__ list,
      const int* __restrict__ cnt, const float* __restrict__ w, float* __restrict__ Xout, int ld){
  __shared__ float wl[6912];
  for(int i=threadIdx.x;i<6912;i+=CTPB) wl[i]=w[i];
  __syncthreads();
  int i = blockIdx.x*CTPB + threadIdx.x;
  if(i >= *cnt) return;
  int v = list[i];
  int d=1<<ld, dm=d-1;
  int x=v&dm, y=(v>>ld)&dm, z=(v>>(2*ld))&dm, b=v>>(3*ld);
  float4 a0=make_float4(0,0,0,0), a1=a0, a2=a0, a3=a0;
  for(int dz=0;dz<3;dz++){ int zz=z+dz-1; if((unsigned)zz>=(unsigned)d) continue;
    for(int dy=0;dy<3;dy++){ int yy=y+dy-1; if((unsigned)yy>=(unsigned)d) continue;
      const float* srow = Xin + ((size_t)vox(b,zz,yy,0,ld)<<4);
      const float* wrow = &wl[((dz*3+dy)*3)<<8];
      for(int dx=0;dx<3;dx++){ int xx=x+dx-1; if((unsigned)xx>=(unsigned)d) continue;
        const float4* sp = (const float4*)(srow + ((size_t)xx<<4));
        float s[16];
        *(float4*)&s[0]=sp[0]; *(float4*)&s[4]=sp[1]; *(float4*)&s[8]=sp[2]; *(float4*)&s[12]=sp[3];
        const float* wt = wrow + (dx<<8);
        #pragma unroll
        for(int ci=0;ci<16;ci++){
          float av=s[ci];
          const float4* wv=(const float4*)(wt + (ci<<4));
          fma4(a0,av,wv[0]); fma4(a1,av,wv[1]); fma4(a2,av,wv[2]); fma4(a3,av,wv[3]);
        }
      }
    }
  }
  float4* o=(float4*)(Xout + ((size_t)v<<4));
  o[0]=a0;o[1]=a1;o[2]=a2;o[3]=a3;
}

// k=4 pad(1,2) conv over active list
__global__ __launch_bounds__(CTPB) void k_conv4_l(const float* __restrict__ Xin, const int* __restrict__ list,
      const int* __restrict__ cnt, const float* __restrict__ w, float* __restrict__ Xout, int ld){
  extern __shared__ float wl4[];
  for(int i=threadIdx.x;i<16384;i+=CTPB) wl4[i]=w[i];
  __syncthreads();
  int i = blockIdx.x*CTPB + threadIdx.x;
  if(i >= *cnt) return;
  int v = list[i];
  int d=1<<ld, dm=d-1;
  int x=v&dm, y=(v>>ld)&dm, z=(v>>(2*ld))&dm, b=v>>(3*ld);
  float4 a0=make_float4(0,0,0,0), a1=a0, a2=a0, a3=a0;
  for(int dz=0;dz<4;dz++){ int zz=z+dz-1; if((unsigned)zz>=(unsigned)d) continue;
    for(int dy=0;dy<4;dy++){ int yy=y+dy-1; if((unsigned)yy>=(unsigned)d) continue;
      const float* srow = Xin + ((size_t)vox(b,zz,yy,0,ld)<<4);
      const float* wrow = &wl4[((dz*4+dy))<<10];
      for(int dx=0;dx<4;dx++){ int xx=x+dx-1; if((unsigned)xx>=(unsigned)d) continue;
        const float4* sp = (const float4*)(srow + ((size_t)xx<<4));
        float s[16];
        *(float4*)&s[0]=sp[0]; *(float4*)&s[4]=sp[1]; *(float4*)&s[8]=sp[2]; *(float4*)&s[12]=sp[3];
        const float* wt = wrow + (dx<<8);
        #pragma unroll
        for(int ci=0;ci<16;ci++){
          float av=s[ci];
          const float4* wv=(const float4*)(wt + (ci<<4));
          fma4(a0,av,wv[0]); fma4(a1,av,wv[1]); fma4(a2,av,wv[2]); fma4(a3,av,wv[3]);
        }
      }
    }
  }
  float4* o=(float4*)(Xout + ((size_t)v<<4));
  o[0]=a0;o[1]=a1;o[2]=a2;o[3]=a3;
}

// strided k=2 s=2 VALID down-conv over coarse active list
__global__ __launch_bounds__(TPB) void k_down_l(const float* __restrict__ Xin, const int* __restrict__ list,
      const int* __restrict__ cnt, const float* __restrict__ w, float* __restrict__ Xout, int ldc){
  __shared__ float wl[2048];
  for(int i=threadIdx.x;i<2048;i+=TPB) wl[i]=w[i];
  __syncthreads();
  int i = blockIdx.x*blockDim.x + threadIdx.x;
  if(i >= *cnt) return;
  int v = list[i];
  int dm=(1<<ldc)-1, ldf=ldc+1;
  int x=v&dm, y=(v>>ldc)&dm, z=(v>>(2*ldc))&dm, b=v>>(3*ldc);
  float4 a0=make_float4(0,0,0,0), a1=a0, a2=a0, a3=a0;
  for(int dz=0;dz<2;dz++) for(int dy=0;dy<2;dy++) for(int dx=0;dx<2;dx++){
    const float4* sp=(const float4*)(Xin + ((size_t)vox(b,2*z+dz,2*y+dy,2*x+dx,ldf)<<4));
    float s[16];
    *(float4*)&s[0]=sp[0]; *(float4*)&s[4]=sp[1]; *(float4*)&s[8]=sp[2]; *(float4*)&s[12]=sp[3];
    const float* wt=&wl[(((dz<<1)|dy)<<1 | dx)<<8];
    #pragma unroll
    for(int ci=0;ci<16;ci++){
      float av=s[ci];
      const float4* wv=(const float4*)(wt+(ci<<4));
      fma4(a0,av,wv[0]); fma4(a1,av,wv[1]); fma4(a2,av,wv[2]); fma4(a3,av,wv[3]);
    }
  }
  float4* o=(float4*)(Xout+((size_t)v<<4));
  o[0]=a0;o[1]=a1;o[2]=a2;o[3]=a3;
}

// conv_transpose k=2 s=2 VALID over fine active list
__global__ __launch_bounds__(TPB) void k_up_l(const float* __restrict__ Xc, const int* __restrict__ list,
      const int* __restrict__ cnt, const float* __restrict__ w, float* __restrict__ Xf, int ldf){
  __shared__ float wl[2048];
  for(int i=threadIdx.x;i<2048;i+=TPB) wl[i]=w[i];
  __syncthreads();
  int i = blockIdx.x*blockDim.x + threadIdx.x;
  if(i >= *cnt) return;
  int v = list[i];
  int dm=(1<<ldf)-1, ldc=ldf-1;
  int x=v&dm, y=(v>>ldf)&dm, z=(v>>(2*ldf))&dm, b=v>>(3*ldf);
  const float4* sp=(const float4*)(Xc + ((size_t)vox(b,z>>1,y>>1,x>>1,ldc)<<4));
  float s[16];
  *(float4*)&s[0]=sp[0]; *(float4*)&s[4]=sp[1]; *(float4*)&s[8]=sp[2]; *(float4*)&s[12]=sp[3];
  int t = ((((z&1)^1)<<1 | ((y&1)^1))<<1) | ((x&1)^1);
  const float* wt=&wl[t<<8];
  float4 a0=make_float4(0,0,0,0), a1=a0, a2=a0, a3=a0;
  #pragma unroll
  for(int ci=0;ci<16;ci++){
    float av=s[ci];
    const float4* wv=(const float4*)(wt+(ci<<4));
    fma4(a0,av,wv[0]); fma4(a1,av,wv[1]); fma4(a2,av,wv[2]); fma4(a3,av,wv[3]);
  }
  float4* o=(float4*)(Xf+((size_t)v<<4));
  o[0]=a0;o[1]=a1;o[2]=a2;o[3]=a3;
}

// masked BN statistics over active list: sums[0..15]=sum, [16..31]=sumsq
__global__ __launch_bounds__(TPB) void k_bnstats(const float* __restrict__ X, const int* __restrict__ list,
        const int* __restrict__ cnt, float* __restrict__ sums){
  int n = *cnt;
  float ls[16], lss[16];
  #pragma unroll
  for(int c=0;c<16;c++){ ls[c]=0.f; lss[c]=0.f; }
  for(int i = blockIdx.x*blockDim.x+threadIdx.x; i<n; i+=gridDim.x*blockDim.x){
    const float* p = X + ((size_t)list[i]<<4);
    #pragma unroll
    for(int c=0;c<16;c++){ float a=p[c]; ls[c]+=a; lss[c]=fmaf(a,a,lss[c]); }
  }
  #pragma unroll
  for(int c=0;c<16;c++){
    for(int o=32;o>0;o>>=1){ ls[c]+=__shfl_down(ls[c],o,64); lss[c]+=__shfl_down(lss[c],o,64); }
  }
  __shared__ float sred[4][32];
  int wv = threadIdx.x>>6, lane = threadIdx.x&63;
  if(lane==0){
    #pragma unroll
    for(int c=0;c<16;c++){ sred[wv][c]=ls[c]; sred[wv][16+c]=lss[c]; }
  }
  __syncthreads();
  if(threadIdx.x<32){
    float t = sred[0][threadIdx.x]+sred[1][threadIdx.x]+sred[2][threadIdx.x]+sred[3][threadIdx.x];
    atomicAdd(&sums[threadIdx.x], t);
  }
}

// fused BN finalize + apply (ReLU, LEAK=0) over active list, in place
__global__ __launch_bounds__(TPB) void k_bnapply(float* __restrict__ X, const int* __restrict__ list,
        const int* __restrict__ cnt, const float* __restrict__ sums,
        const float* __restrict__ g, const float* __restrict__ bta){
  __shared__ float sc[16], sh[16];
  if(threadIdx.x<16){
    int c=threadIdx.x;
    float nact = (float)(*cnt); if(nact<1.f) nact=1.f;
    float mean = sums[c]/nact;
    float var = sums[16+c]/nact - mean*mean;
    float s = g[c]/sqrtf(var+1e-4f);
    sc[c]=s; sh[c]=fmaf(-mean,s,bta[c]);
  }
  __syncthreads();
  int i = blockIdx.x*blockDim.x + threadIdx.x;
  if(i>=*cnt) return;
  float* p = X + ((size_t)list[i]<<4);
  #pragma unroll
  for(int c=0;c<16;c++){
    float xh = fmaf(p[c], sc[c], sh[c]);
    p[c] = xh>0.f ? xh : 0.f;
  }
}

// hidden = NCDHW flatten of level-3 features
__global__ __launch_bounds__(TPB) void k_hidden(const float* __restrict__ X3, float* __restrict__ out){
  int i = blockIdx.x*blockDim.x + threadIdx.x;
  if(i>=4*8192) return;
  int b=i>>13, r=i&8191, c=r>>9, s=r&511;
  out[i] = X3[(((size_t)((b<<9)|s))<<4)|c];
}

// output conv 16 -> 1, k=3 SAME, over active list
__global__ __launch_bounds__(TPB) void k_final_l(const float* __restrict__ Xin, const int* __restrict__ list,
      const int* __restrict__ cnt, const float* __restrict__ w, float* __restrict__ out){
  __shared__ float wl[432];
  for(int i=threadIdx.x;i<432;i+=TPB) wl[i]=w[i];
  __syncthreads();
  int i = blockIdx.x*blockDim.x + threadIdx.x;
  if(i >= *cnt) return;
  int v = list[i];
  float acc=0.f;
  int x=v&63, y=(v>>6)&63, z=(v>>12)&63, b=v>>18;
  for(int dz=0;dz<3;dz++){ int zz=z+dz-1; if((unsigned)zz>=64u) continue;
    for(int dy=0;dy<3;dy++){ int yy=y+dy-1; if((unsigned)yy>=64u) continue;
      for(int dx=0;dx<3;dx++){ int xx=x+dx-1; if((unsigned)xx>=64u) continue;
        const float* sp = Xin + ((size_t)vox(b,zz,yy,xx,6)<<4);
        const float* wt = &wl[((dz*3+dy)*3+dx)<<4];
        #pragma unroll
        for(int ci=0;ci<16;ci++) acc = fmaf(sp[ci], wt[ci], acc);
      }
    }
  }
  out[v]=acc;
}

static inline int nb(int n){ return (n+TPB-1)/TPB; }
static inline int nbC(int n){ return (n+CTPB-1)/CTPB; }
static inline size_t rbytes(int ld){ return ((size_t)4<<(3*ld))*64; }  // voxels * 16ch * 4B

extern "C" void kernel_launch(void* const* d_in, const int* in_sizes, int n_in,
                              void* d_out, int out_size, void* d_ws, size_t ws_size,
                              hipStream_t stream){
  const float* data   = (const float*)d_in[0];
  const int*   cl     = (const int*)d_in[1];
  const float* w_prep = (const float*)d_in[2];
  const float* enc_g  = (const float*)d_in[3];
  const float* enc_b  = (const float*)d_in[4];
  const float* enc_ws = (const float*)d_in[5];
  const float* enc_wd = (const float*)d_in[6];
  const float* dec_g  = (const float*)d_in[7];
  const float* dec_b  = (const float*)d_in[8];
  const float* dec_wu = (const float*)d_in[9];
  const float* dec_w3 = (const float*)d_in[10];
  const float* dec_w4 = (const float*)d_in[11];
  const float* w_out  = (const float*)d_in[12];
  int N = in_sizes[0]/5;
  const int n0 = 4<<18;

  float* ws = (float*)d_ws;
  float* X  = ws;                         // 64MB
  float* Y  = X + (size_t)n0*16;          // 64MB
  float* c0 = Y + (size_t)n0*16;          // 4MB
  float* m0 = c0 + n0;                    // 4MB
  float* m1 = m0 + n0;                    // 512KB
  float* m2 = m1 + (4<<15);               // 64KB
  float* m3 = m2 + (4<<12);               // 8KB
  float* sums = m3 + (4<<9);              // 6*32 floats
  int* counts = (int*)(sums + 192);       // 16 ints (slots 0..3: la L0..L3; 4..6: lb L0..L2)
  int* l0a = counts + 16;                 // cap 262144 (count <= N = 200000)
  int* l0b = l0a + 262144;
  int* l1a = l0b + 262144;
  int* l1b = l1a + (4<<15);
  int* l2a = l1b + (4<<15);
  int* l2b = l2a + (4<<12);
  int* l3  = l2b + (4<<12);
  float* out = (float*)d_out;

  float* masks[4] = {m0,m1,m2,m3};
  int* la[4] = {l0a,l1a,l2a,l3};
  int* lb[3] = {l0b,l1b,l2b};
  int b0 = N < 262144 ? N : 262144;
  int bounds[4] = {b0, 4<<15, 4<<12, 4<<9};

  // zero sums + counts (contiguous), count grid
  hipMemsetAsync(sums, 0, 192*4 + 16*4, stream);
  hipMemsetAsync(c0, 0, (size_t)n0*4, stream);
  k_scatter<<<nb(N),TPB,0,stream>>>(data, cl, N, c0);
  k_compact0<<<nb(n0),TPB,0,stream>>>(c0, m0, n0, l0a, counts+0);
  hipMemsetAsync(X, 0, rbytes(6), stream);
  k_prep_l<<<nb(bounds[0]),TPB,0,stream>>>(c0, l0a, counts+0, w_prep, X);

  float* cur=X; float* oth=Y;
  int ld=6;
  // encoder
  for(int i=0;i<3;i++){
    int gs = nb(bounds[i]); if(gs>384) gs=384;
    k_bnstats<<<gs,TPB,0,stream>>>(cur, la[i], counts+i, sums+i*32);
    k_bnapply<<<nb(bounds[i]),TPB,0,stream>>>(cur, la[i], counts+i, sums+i*32, enc_g+16*i, enc_b+16*i);
    hipMemsetAsync(oth, 0, rbytes(ld), stream);
    k_conv3_l<<<nbC(bounds[i]),CTPB,0,stream>>>(cur, la[i], counts+i, enc_ws+6912*i, oth, ld);
    { float* t=cur; cur=oth; oth=t; }
    int ldc=ld-1, nc=4<<(3*ldc);
    k_downmask_compact<<<nb(nc),TPB,0,stream>>>(masks[i], masks[i+1], ldc, nc, la[i+1], counts+(i+1));
    hipMemsetAsync(oth, 0, rbytes(ldc), stream);
    k_down_l<<<nb(bounds[i+1]),TPB,0,stream>>>(cur, la[i+1], counts+(i+1), enc_wd+2048*i, oth, ldc);
    { float* t=cur; cur=oth; oth=t; }
    ld=ldc;
  }
  // hidden (level 3, before decoder BN)
  k_hidden<<<nb(4*8192),TPB,0,stream>>>(cur, out);
  // decoder
  for(int j=0;j<3;j++){
    int lvl=2-j;
    const int* listC; const int* cc; int cb;
    if(j==0){ listC=la[3]; cc=counts+3; cb=bounds[3]; }
    else    { listC=lb[lvl+1]; cc=counts+4+(lvl+1); cb=bounds[lvl+1]; }
    int gs = nb(cb); if(gs>384) gs=384;
    k_bnstats<<<gs,TPB,0,stream>>>(cur, listC, cc, sums+(3+j)*32);
    k_bnapply<<<nb(cb),TPB,0,stream>>>(cur, listC, cc, sums+(3+j)*32, dec_g+16*j, dec_b+16*j);
    int ldf=ld+1;
    hipMemsetAsync(oth, 0, rbytes(ldf), stream);
    k_up_l<<<nb(bounds[lvl]),TPB,0,stream>>>(cur, la[lvl], counts+lvl, dec_wu+2048*j, oth, ldf);
    { float* t=cur; cur=oth; oth=t; }
    hipMemsetAsync(oth, 0, rbytes(ldf), stream);
    k_conv3_l<<<nbC(bounds[lvl]),CTPB,0,stream>>>(cur, la[lvl], counts+lvl, dec_w3+6912*j, oth, ldf);
    { float* t=cur; cur=oth; oth=t; }
    // zero dropped sites in BOTH cur and oth => conv4 may skip its output memset
    k_sparsify_compact<<<nb(bounds[lvl]),TPB,0,stream>>>(cur, oth, la[lvl], counts+lvl, lb[lvl], counts+4+lvl);
    k_conv4_l<<<nbC(bounds[lvl]),CTPB,65536,stream>>>(cur, lb[lvl], counts+4+lvl, dec_w4+16384*j, oth, ldf);
    { float* t=cur; cur=oth; oth=t; }
    ld=ldf;
  }
  hipMemsetAsync(out+32768, 0, (size_t)n0*4, stream);
  k_final_l<<<nb(bounds[0]),TPB,0,stream>>>(cur, lb[0], counts+4, w_out, out+32768);
}

// Round 3
// 957.828 us; speedup vs baseline: 1.7598x; 1.1909x over previous
//
#include <hip/hip_runtime.h>

#define TPB 256
#define CTPB 512

__device__ __forceinline__ void fma4(float4& a, float s, const float4 b){
  a.x = fmaf(s,b.x,a.x); a.y = fmaf(s,b.y,a.y);
  a.z = fmaf(s,b.z,a.z); a.w = fmaf(s,b.w,a.w);
}

__device__ __forceinline__ int vox(int b,int z,int y,int x,int ld){
  return ((((((b<<ld)|z)<<ld)|y)<<ld)|x);
}

// block-hierarchical list append: ballot -> LDS atomic per wave -> ONE global atomic per block.
// Must be called by ALL threads of a TPB-sized block (a=false for non-participants).
__device__ __forceinline__ void append_list(bool a, int v, int* __restrict__ list, int* __restrict__ cnt){
  __shared__ int lcnt, lbase;
  __shared__ int woff[TPB/64];
  if(threadIdx.x==0) lcnt=0;
  __syncthreads();
  unsigned long long bl = __ballot(a);
  int lane = threadIdx.x & 63;
  int wv = threadIdx.x >> 6;
  if(lane==0){ int pop=__popcll(bl); woff[wv] = pop ? atomicAdd(&lcnt,pop) : 0; }
  __syncthreads();
  if(threadIdx.x==0 && lcnt) lbase = atomicAdd(cnt, lcnt);
  __syncthreads();
  if(a) list[lbase + woff[wv] + __popcll(bl & ((1ull<<lane)-1ull))] = v;
}

// scatter points into count grid; first hitter of a voxel appends it to the L0 active list
__global__ __launch_bounds__(TPB) void k_scatter_compact(const float* __restrict__ data, const int* __restrict__ cl,
        int n, float* __restrict__ c0, int* __restrict__ list, int* __restrict__ cnt){
  int i = blockIdx.x*blockDim.x + threadIdx.x;
  bool first=false; int v=0;
  if(i<n){
    int z = (int)data[i*5+0];
    int y = (int)data[i*5+1];
    int x = (int)data[i*5+2];
    v = vox(cl[i],z,y,x,6);
    float old = atomicAdd(&c0[v], 1.0f);
    first = (old==0.0f);
  }
  append_list(first, v, list, cnt);
}

// mark parent (coarse) voxel of each active fine voxel: plain store of 1.0
__global__ __launch_bounds__(TPB) void k_markparent(const int* __restrict__ list, const int* __restrict__ cnt,
                                                    float* __restrict__ mc, int ldf){
  int i = blockIdx.x*blockDim.x + threadIdx.x;
  if(i>=*cnt) return;
  int v = list[i];
  int dm=(1<<ldf)-1;
  int x=v&dm, y=(v>>ldf)&dm, z=(v>>(2*ldf))&dm, b=v>>(3*ldf);
  mc[vox(b,z>>1,y>>1,x>>1,ldf-1)] = 1.0f;
}

// compact a (small) occupancy grid into a list
__global__ __launch_bounds__(TPB) void k_compact_grid(const float* __restrict__ m, int n,
                                                      int* __restrict__ list, int* __restrict__ cnt){
  int i = blockIdx.x*blockDim.x + threadIdx.x;
  bool a = (i<n) && (m[i]!=0.f);
  append_list(a, i, list, cnt);
}

// sparsify: keep sites with ch0 > 0; zero dropped sites in BOTH buffers; compact keepers
__global__ __launch_bounds__(TPB) void k_sparsify_compact(float* __restrict__ X, float* __restrict__ Y,
        const int* __restrict__ listA, const int* __restrict__ cntA,
        int* __restrict__ listB, int* __restrict__ cntB){
  int i = blockIdx.x*blockDim.x + threadIdx.x;
  bool keep=false; int v=0;
  if(i < *cntA){
    v = listA[i];
    keep = X[(size_t)v<<4] > 0.f;
    if(!keep){
      float4 zz = make_float4(0,0,0,0);
      float4* px=(float4*)(X+((size_t)v<<4)); px[0]=zz;px[1]=zz;px[2]=zz;px[3]=zz;
      float4* py=(float4*)(Y+((size_t)v<<4)); py[0]=zz;py[1]=zz;py[2]=zz;py[3]=zz;
    }
  }
  append_list(keep, v, listB, cntB);
}

// prepare: 1 -> 16 channels, k=3 SAME, over active list
__global__ __launch_bounds__(TPB) void k_prep_l(const float* __restrict__ c0, const int* __restrict__ list,
          const int* __restrict__ cnt, const float* __restrict__ w, float* __restrict__ X){
  __shared__ float wl[432];
  for(int i=threadIdx.x;i<432;i+=TPB) wl[i]=w[i];
  __syncthreads();
  int i = blockIdx.x*blockDim.x + threadIdx.x;
  if(i >= *cnt) return;
  int v = list[i];
  int x=v&63, y=(v>>6)&63, z=(v>>12)&63, b=v>>18;
  float4 a0=make_float4(0,0,0,0), a1=a0, a2=a0, a3=a0;
  for(int dz=0;dz<3;dz++){ int zz=z+dz-1; if((unsigned)zz>=64u) continue;
    for(int dy=0;dy<3;dy++){ int yy=y+dy-1; if((unsigned)yy>=64u) continue;
      for(int dx=0;dx<3;dx++){ int xx=x+dx-1; if((unsigned)xx>=64u) continue;
        float av = c0[vox(b,zz,yy,xx,6)];
        if(av==0.f) continue;
        const float4* wv = (const float4*)&wl[((dz*3+dy)*3+dx)<<4];
        fma4(a0,av,wv[0]); fma4(a1,av,wv[1]); fma4(a2,av,wv[2]); fma4(a3,av,wv[3]);
      }
    }
  }
  float4* o = (float4*)(X + ((size_t)v<<4));
  o[0]=a0; o[1]=a1; o[2]=a2; o[3]=a3;
}

// 16->16 k=3 SAME conv over active list
__global__ __launch_bounds__(CTPB) void k_conv3_l(const float* __restrict__ Xin, const int* __restrict__ list,
      const int* __restrict__ cnt, const float* __restrict__ w, float* __restrict__ Xout, int ld){
  __shared__ float wl[6912];
  for(int i=threadIdx.x;i<6912;i+=CTPB) wl[i]=w[i];
  __syncthreads();
  int i = blockIdx.x*CTPB + threadIdx.x;
  if(i >= *cnt) return;
  int v = list[i];
  int d=1<<ld, dm=d-1;
  int x=v&dm, y=(v>>ld)&dm, z=(v>>(2*ld))&dm, b=v>>(3*ld);
  float4 a0=make_float4(0,0,0,0), a1=a0, a2=a0, a3=a0;
  for(int dz=0;dz<3;dz++){ int zz=z+dz-1; if((unsigned)zz>=(unsigned)d) continue;
    for(int dy=0;dy<3;dy++){ int yy=y+dy-1; if((unsigned)yy>=(unsigned)d) continue;
      const float* srow = Xin + ((size_t)vox(b,zz,yy,0,ld)<<4);
      const float* wrow = &wl[((dz*3+dy)*3)<<8];
      for(int dx=0;dx<3;dx++){ int xx=x+dx-1; if((unsigned)xx>=(unsigned)d) continue;
        const float4* sp = (const float4*)(srow + ((size_t)xx<<4));
        float s[16];
        *(float4*)&s[0]=sp[0]; *(float4*)&s[4]=sp[1]; *(float4*)&s[8]=sp[2]; *(float4*)&s[12]=sp[3];
        const float* wt = wrow + (dx<<8);
        #pragma unroll
        for(int ci=0;ci<16;ci++){
          float av=s[ci];
          const float4* wv=(const float4*)(wt + (ci<<4));
          fma4(a0,av,wv[0]); fma4(a1,av,wv[1]); fma4(a2,av,wv[2]); fma4(a3,av,wv[3]);
        }
      }
    }
  }
  float4* o=(float4*)(Xout + ((size_t)v<<4));
  o[0]=a0;o[1]=a1;o[2]=a2;o[3]=a3;
}

// k=4 pad(1,2) conv over active list
__global__ __launch_bounds__(CTPB) void k_conv4_l(const float* __restrict__ Xin, const int* __restrict__ list,
      const int* __restrict__ cnt, const float* __restrict__ w, float* __restrict__ Xout, int ld){
  extern __shared__ float wl4[];
  for(int i=threadIdx.x;i<16384;i+=CTPB) wl4[i]=w[i];
  __syncthreads();
  int i = blockIdx.x*CTPB + threadIdx.x;
  if(i >= *cnt) return;
  int v = list[i];
  int d=1<<ld, dm=d-1;
  int x=v&dm, y=(v>>ld)&dm, z=(v>>(2*ld))&dm, b=v>>(3*ld);
  float4 a0=make_float4(0,0,0,0), a1=a0, a2=a0, a3=a0;
  for(int dz=0;dz<4;dz++){ int zz=z+dz-1; if((unsigned)zz>=(unsigned)d) continue;
    for(int dy=0;dy<4;dy++){ int yy=y+dy-1; if((unsigned)yy>=(unsigned)d) continue;
      const float* srow = Xin + ((size_t)vox(b,zz,yy,0,ld)<<4);
      const float* wrow = &wl4[((dz*4+dy))<<10];
      for(int dx=0;dx<4;dx++){ int xx=x+dx-1; if((unsigned)xx>=(unsigned)d) continue;
        const float4* sp = (const float4*)(srow + ((size_t)xx<<4));
        float s[16];
        *(float4*)&s[0]=sp[0]; *(float4*)&s[4]=sp[1]; *(float4*)&s[8]=sp[2]; *(float4*)&s[12]=sp[3];
        const float* wt = wrow + (dx<<8);
        #pragma unroll
        for(int ci=0;ci<16;ci++){
          float av=s[ci];
          const float4* wv=(const float4*)(wt + (ci<<4));
          fma4(a0,av,wv[0]); fma4(a1,av,wv[1]); fma4(a2,av,wv[2]); fma4(a3,av,wv[3]);
        }
      }
    }
  }
  float4* o=(float4*)(Xout + ((size_t)v<<4));
  o[0]=a0;o[1]=a1;o[2]=a2;o[3]=a3;
}

// strided k=2 s=2 VALID down-conv over coarse active list
__global__ __launch_bounds__(TPB) void k_down_l(const float* __restrict__ Xin, const int* __restrict__ list,
      const int* __restrict__ cnt, const float* __restrict__ w, float* __restrict__ Xout, int ldc){
  __shared__ float wl[2048];
  for(int i=threadIdx.x;i<2048;i+=TPB) wl[i]=w[i];
  __syncthreads();
  int i = blockIdx.x*blockDim.x + threadIdx.x;
  if(i >= *cnt) return;
  int v = list[i];
  int dm=(1<<ldc)-1, ldf=ldc+1;
  int x=v&dm, y=(v>>ldc)&dm, z=(v>>(2*ldc))&dm, b=v>>(3*ldc);
  float4 a0=make_float4(0,0,0,0), a1=a0, a2=a0, a3=a0;
  for(int dz=0;dz<2;dz++) for(int dy=0;dy<2;dy++) for(int dx=0;dx<2;dx++){
    const float4* sp=(const float4*)(Xin + ((size_t)vox(b,2*z+dz,2*y+dy,2*x+dx,ldf)<<4));
    float s[16];
    *(float4*)&s[0]=sp[0]; *(float4*)&s[4]=sp[1]; *(float4*)&s[8]=sp[2]; *(float4*)&s[12]=sp[3];
    const float* wt=&wl[(((dz<<1)|dy)<<1 | dx)<<8];
    #pragma unroll
    for(int ci=0;ci<16;ci++){
      float av=s[ci];
      const float4* wv=(const float4*)(wt+(ci<<4));
      fma4(a0,av,wv[0]); fma4(a1,av,wv[1]); fma4(a2,av,wv[2]); fma4(a3,av,wv[3]);
    }
  }
  float4* o=(float4*)(Xout+((size_t)v<<4));
  o[0]=a0;o[1]=a1;o[2]=a2;o[3]=a3;
}

// conv_transpose k=2 s=2 VALID over fine active list
__global__ __launch_bounds__(TPB) void k_up_l(const float* __restrict__ Xc, const int* __restrict__ list,
      const int* __restrict__ cnt, const float* __restrict__ w, float* __restrict__ Xf, int ldf){
  __shared__ float wl[2048];
  for(int i=threadIdx.x;i<2048;i+=TPB) wl[i]=w[i];
  __syncthreads();
  int i = blockIdx.x*blockDim.x + threadIdx.x;
  if(i >= *cnt) return;
  int v = list[i];
  int dm=(1<<ldf)-1, ldc=ldf-1;
  int x=v&dm, y=(v>>ldf)&dm, z=(v>>(2*ldf))&dm, b=v>>(3*ldf);
  const float4* sp=(const float4*)(Xc + ((size_t)vox(b,z>>1,y>>1,x>>1,ldc)<<4));
  float s[16];
  *(float4*)&s[0]=sp[0]; *(float4*)&s[4]=sp[1]; *(float4*)&s[8]=sp[2]; *(float4*)&s[12]=sp[3];
  int t = ((((z&1)^1)<<1 | ((y&1)^1))<<1) | ((x&1)^1);
  const float* wt=&wl[t<<8];
  float4 a0=make_float4(0,0,0,0), a1=a0, a2=a0, a3=a0;
  #pragma unroll
  for(int ci=0;ci<16;ci++){
    float av=s[ci];
    const float4* wv=(const float4*)(wt+(ci<<4));
    fma4(a0,av,wv[0]); fma4(a1,av,wv[1]); fma4(a2,av,wv[2]); fma4(a3,av,wv[3]);
  }
  float4* o=(float4*)(Xf+((size_t)v<<4));
  o[0]=a0;o[1]=a1;o[2]=a2;o[3]=a3;
}

// BN statistics over active list: sums[0..15]=sum, [16..31]=sumsq
__global__ __launch_bounds__(TPB) void k_bnstats(const float* __restrict__ X, const int* __restrict__ list,
        const int* __restrict__ cnt, float* __restrict__ sums){
  int n = *cnt;
  float ls[16], lss[16];
  #pragma unroll
  for(int c=0;c<16;c++){ ls[c]=0.f; lss[c]=0.f; }
  for(int i = blockIdx.x*blockDim.x+threadIdx.x; i<n; i+=gridDim.x*blockDim.x){
    const float* p = X + ((size_t)list[i]<<4);
    #pragma unroll
    for(int c=0;c<16;c++){ float a=p[c]; ls[c]+=a; lss[c]=fmaf(a,a,lss[c]); }
  }
  #pragma unroll
  for(int c=0;c<16;c++){
    for(int o=32;o>0;o>>=1){ ls[c]+=__shfl_down(ls[c],o,64); lss[c]+=__shfl_down(lss[c],o,64); }
  }
  __shared__ float sred[4][32];
  int wv = threadIdx.x>>6, lane = threadIdx.x&63;
  if(lane==0){
    #pragma unroll
    for(int c=0;c<16;c++){ sred[wv][c]=ls[c]; sred[wv][16+c]=lss[c]; }
  }
  __syncthreads();
  if(threadIdx.x<32){
    float t = sred[0][threadIdx.x]+sred[1][threadIdx.x]+sred[2][threadIdx.x]+sred[3][threadIdx.x];
    atomicAdd(&sums[threadIdx.x], t);
  }
}

// fused BN finalize + apply (ReLU, LEAK=0) over active list, in place
__global__ __launch_bounds__(TPB) void k_bnapply(float* __restrict__ X, const int* __restrict__ list,
        const int* __restrict__ cnt, const float* __restrict__ sums,
        const float* __restrict__ g, const float* __restrict__ bta){
  __shared__ float sc[16], sh[16];
  if(threadIdx.x<16){
    int c=threadIdx.x;
    float nact = (float)(*cnt); if(nact<1.f) nact=1.f;
    float mean = sums[c]/nact;
    float var = sums[16+c]/nact - mean*mean;
    float s = g[c]/sqrtf(var+1e-4f);
    sc[c]=s; sh[c]=fmaf(-mean,s,bta[c]);
  }
  __syncthreads();
  int i = blockIdx.x*blockDim.x + threadIdx.x;
  if(i>=*cnt) return;
  float* p = X + ((size_t)list[i]<<4);
  #pragma unroll
  for(int c=0;c<16;c++){
    float xh = fmaf(p[c], sc[c], sh[c]);
    p[c] = xh>0.f ? xh : 0.f;
  }
}

// hidden = NCDHW flatten of level-3 features
__global__ __launch_bounds__(TPB) void k_hidden(const float* __restrict__ X3, float* __restrict__ out){
  int i = blockIdx.x*blockDim.x + threadIdx.x;
  if(i>=4*8192) return;
  int b=i>>13, r=i&8191, c=r>>9, s=r&511;
  out[i] = X3[(((size_t)((b<<9)|s))<<4)|c];
}

// output conv 16 -> 1, k=3 SAME, over active list
__global__ __launch_bounds__(TPB) void k_final_l(const float* __restrict__ Xin, const int* __restrict__ list,
      const int* __restrict__ cnt, const float* __restrict__ w, float* __restrict__ out){
  __shared__ float wl[432];
  for(int i=threadIdx.x;i<432;i+=TPB) wl[i]=w[i];
  __syncthreads();
  int i = blockIdx.x*blockDim.x + threadIdx.x;
  if(i >= *cnt) return;
  int v = list[i];
  float acc=0.f;
  int x=v&63, y=(v>>6)&63, z=(v>>12)&63, b=v>>18;
  for(int dz=0;dz<3;dz++){ int zz=z+dz-1; if((unsigned)zz>=64u) continue;
    for(int dy=0;dy<3;dy++){ int yy=y+dy-1; if((unsigned)yy>=64u) continue;
      for(int dx=0;dx<3;dx++){ int xx=x+dx-1; if((unsigned)xx>=64u) continue;
        const float* sp = Xin + ((size_t)vox(b,zz,yy,xx,6)<<4);
        const float* wt = &wl[((dz*3+dy)*3+dx)<<4];
        #pragma unroll
        for(int ci=0;ci<16;ci++) acc = fmaf(sp[ci], wt[ci], acc);
      }
    }
  }
  out[v]=acc;
}

static inline int nb(int n){ return (n+TPB-1)/TPB; }
static inline int nbC(int n){ return (n+CTPB-1)/CTPB; }
static inline size_t rbytes(int ld){ return ((size_t)4<<(3*ld))*64; }  // voxels * 16ch * 4B

extern "C" void kernel_launch(void* const* d_in, const int* in_sizes, int n_in,
                              void* d_out, int out_size, void* d_ws, size_t ws_size,
                              hipStream_t stream){
  const float* data   = (const float*)d_in[0];
  const int*   cl     = (const int*)d_in[1];
  const float* w_prep = (const float*)d_in[2];
  const float* enc_g  = (const float*)d_in[3];
  const float* enc_b  = (const float*)d_in[4];
  const float* enc_ws = (const float*)d_in[5];
  const float* enc_wd = (const float*)d_in[6];
  const float* dec_g  = (const float*)d_in[7];
  const float* dec_b  = (const float*)d_in[8];
  const float* dec_wu = (const float*)d_in[9];
  const float* dec_w3 = (const float*)d_in[10];
  const float* dec_w4 = (const float*)d_in[11];
  const float* w_out  = (const float*)d_in[12];
  int N = in_sizes[0]/5;
  const int n0 = 4<<18;

  float* ws = (float*)d_ws;
  float* X  = ws;                         // 64MB
  float* Y  = X + (size_t)n0*16;          // 64MB
  float* c0 = Y + (size_t)n0*16;          // 4MB
  float* m1 = c0 + n0;                    // 512KB  (coarse occupancy grids, contiguous)
  float* m2 = m1 + (4<<15);               // 64KB
  float* m3 = m2 + (4<<12);               // 8KB
  float* sums = m3 + (4<<9);              // 6*32 floats
  int* counts = (int*)(sums + 192);       // 16 ints (0..3: la L0..L3; 4..6: lb L0..L2)
  int* l0a = counts + 16;
  int* l0b = l0a + 262144;
  int* l1a = l0b + 262144;
  int* l1b = l1a + (4<<15);
  int* l2a = l1b + (4<<15);
  int* l2b = l2a + (4<<12);
  int* l3  = l2b + (4<<12);
  float* out = (float*)d_out;

  float* masks[4] = {nullptr,m1,m2,m3};
  int* la[4] = {l0a,l1a,l2a,l3};
  int* lb[3] = {l0b,l1b,l2b};
  int b0 = N < 262144 ? N : 262144;
  int bounds[4] = {b0, 4<<15, 4<<12, 4<<9};

  hipMemsetAsync(sums, 0, 192*4 + 16*4, stream);
  hipMemsetAsync(c0, 0, (size_t)n0*4, stream);
  hipMemsetAsync(m1, 0, ((4<<15)+(4<<12)+(4<<9))*4, stream);
  hipMemsetAsync(X, 0, rbytes(6), stream);
  k_scatter_compact<<<nb(N),TPB,0,stream>>>(data, cl, N, c0, l0a, counts+0);
  k_prep_l<<<nb(bounds[0]),TPB,0,stream>>>(c0, l0a, counts+0, w_prep, X);

  float* cur=X; float* oth=Y;
  int ld=6;
  // encoder
  for(int i=0;i<3;i++){
    int gs = nb(bounds[i]); if(gs>384) gs=384;
    k_bnstats<<<gs,TPB,0,stream>>>(cur, la[i], counts+i, sums+i*32);
    k_bnapply<<<nb(bounds[i]),TPB,0,stream>>>(cur, la[i], counts+i, sums+i*32, enc_g+16*i, enc_b+16*i);
    hipMemsetAsync(oth, 0, rbytes(ld), stream);
    k_conv3_l<<<nbC(bounds[i]),CTPB,0,stream>>>(cur, la[i], counts+i, enc_ws+6912*i, oth, ld);
    { float* t=cur; cur=oth; oth=t; }
    int ldc=ld-1, nc=4<<(3*ldc);
    k_markparent<<<nb(bounds[i]),TPB,0,stream>>>(la[i], counts+i, masks[i+1], ld);
    k_compact_grid<<<nb(nc),TPB,0,stream>>>(masks[i+1], nc, la[i+1], counts+(i+1));
    hipMemsetAsync(oth, 0, rbytes(ldc), stream);
    k_down_l<<<nb(bounds[i+1]),TPB,0,stream>>>(cur, la[i+1], counts+(i+1), enc_wd+2048*i, oth, ldc);
    { float* t=cur; cur=oth; oth=t; }
    ld=ldc;
  }
  // hidden (level 3, before decoder BN)
  k_hidden<<<nb(4*8192),TPB,0,stream>>>(cur, out);
  // decoder
  for(int j=0;j<3;j++){
    int lvl=2-j;
    const int* listC; const int* cc; int cb;
    if(j==0){ listC=la[3]; cc=counts+3; cb=bounds[3]; }
    else    { listC=lb[lvl+1]; cc=counts+4+(lvl+1); cb=bounds[lvl+1]; }
    int gs = nb(cb); if(gs>384) gs=384;
    k_bnstats<<<gs,TPB,0,stream>>>(cur, listC, cc, sums+(3+j)*32);
    k_bnapply<<<nb(cb),TPB,0,stream>>>(cur, listC, cc, sums+(3+j)*32, dec_g+16*j, dec_b+16*j);
    int ldf=ld+1;
    hipMemsetAsync(oth, 0, rbytes(ldf), stream);
    k_up_l<<<nb(bounds[lvl]),TPB,0,stream>>>(cur, la[lvl], counts+lvl, dec_wu+2048*j, oth, ldf);
    { float* t=cur; cur=oth; oth=t; }
    hipMemsetAsync(oth, 0, rbytes(ldf), stream);
    k_conv3_l<<<nbC(bounds[lvl]),CTPB,0,stream>>>(cur, la[lvl], counts+lvl, dec_w3+6912*j, oth, ldf);
    { float* t=cur; cur=oth; oth=t; }
    // zero dropped sites in BOTH cur and oth => conv4 needs no output memset
    k_sparsify_compact<<<nb(bounds[lvl]),TPB,0,stream>>>(cur, oth, la[lvl], counts+lvl, lb[lvl], counts+4+lvl);
    k_conv4_l<<<nbC(bounds[lvl]),CTPB,65536,stream>>>(cur, lb[lvl], counts+4+lvl, dec_w4+16384*j, oth, ldf);
    { float* t=cur; cur=oth; oth=t; }
    ld=ldf;
  }
  hipMemsetAsync(out+32768, 0, (size_t)n0*4, stream);
  k_final_l<<<nb(bounds[0]),TPB,0,stream>>>(cur, lb[0], counts+4, w_out, out+32768);
}

// Round 4
// 848.398 us; speedup vs baseline: 1.9868x; 1.1290x over previous
//
#include <hip/hip_runtime.h>

#define TPB 256
#define CTPB 512

__device__ __forceinline__ void fma4(float4& a, float s, const float4 b){
  a.x = fmaf(s,b.x,a.x); a.y = fmaf(s,b.y,a.y);
  a.z = fmaf(s,b.z,a.z); a.w = fmaf(s,b.w,a.w);
}

__device__ __forceinline__ int vox(int b,int z,int y,int x,int ld){
  return ((((((b<<ld)|z)<<ld)|y)<<ld)|x);
}

__device__ __forceinline__ float chan(const float4&a0,const float4&a1,const float4&a2,const float4&a3,int c){
  const float4& f = (c<4)?a0:((c<8)?a1:((c<12)?a2:a3));
  int r=c&3;
  return r==0?f.x:(r==1?f.y:(r==2?f.z:f.w));
}

// block-hierarchical list append: ballot -> LDS -> ONE global atomic per block.
// ALL threads of the block must call (a=false for non-participants).
__device__ __forceinline__ void append_list(bool a, int v, int* __restrict__ list, int* __restrict__ cnt){
  __shared__ int lcnt, lbase;
  __shared__ int woff[TPB/64];
  if(threadIdx.x==0) lcnt=0;
  __syncthreads();
  unsigned long long bl = __ballot(a);
  int lane = threadIdx.x & 63;
  int wv = threadIdx.x >> 6;
  if(lane==0){ int pop=__popcll(bl); woff[wv] = pop ? atomicAdd(&lcnt,pop) : 0; }
  __syncthreads();
  if(threadIdx.x==0 && lcnt) lbase = atomicAdd(cnt, lcnt);
  __syncthreads();
  if(a) list[lbase + woff[wv] + __popcll(bl & ((1ull<<lane)-1ull))] = v;
}

// fused block stats reduction: sum + sumsq of 16-channel values into gsums[0..31]
__device__ __forceinline__ void stats_reduce(const float4&a0,const float4&a1,const float4&a2,const float4&a3,
                                             float* red /* >= (blockDim/64)*32 */, float* __restrict__ gsums){
  int lane=threadIdx.x&63, wv=threadIdx.x>>6, nw=blockDim.x>>6;
  #pragma unroll
  for(int c=0;c<16;c++){
    float x = chan(a0,a1,a2,a3,c);
    float q = x*x;
    for(int o=32;o>0;o>>=1){ x+=__shfl_down(x,o,64); q+=__shfl_down(q,o,64); }
    if(lane==0){ red[wv*32+c]=x; red[wv*32+16+c]=q; }
  }
  __syncthreads();
  if(threadIdx.x<32){
    float t=0.f;
    for(int w=0;w<nw;w++) t+=red[w*32+threadIdx.x];
    atomicAdd(&gsums[threadIdx.x], t);
  }
}

__global__ __launch_bounds__(TPB) void k_scatter(const float* __restrict__ data, const int* __restrict__ cl,
                                                 int n, float* __restrict__ c0){
  int i = blockIdx.x*blockDim.x + threadIdx.x;
  if(i>=n) return;
  int z=(int)data[i*5+0], y=(int)data[i*5+1], x=(int)data[i*5+2];
  atomicAdd(&c0[vox(cl[i],z,y,x,6)], 1.0f);
}

// ---- ordered 3-phase compaction of the L0 occupancy grid ----
__global__ __launch_bounds__(TPB) void k_cnt0(const float* __restrict__ c0, int n, int* __restrict__ bc){
  int i = blockIdx.x*TPB + threadIdx.x;
  bool a = (i<n) && (c0[i]>0.f);
  unsigned long long bl = __ballot(a);
  __shared__ int wcnt[TPB/64];
  int lane=threadIdx.x&63, wv=threadIdx.x>>6;
  if(lane==0) wcnt[wv]=__popcll(bl);
  __syncthreads();
  if(threadIdx.x==0) bc[blockIdx.x]=wcnt[0]+wcnt[1]+wcnt[2]+wcnt[3];
}

__global__ __launch_bounds__(1024) void k_scan0(int* __restrict__ bc, int nb, int* __restrict__ total){
  __shared__ int s[1024];
  int t=threadIdx.x, b4=t*4;
  int v0 = (b4+0<nb)?bc[b4+0]:0;
  int v1 = (b4+1<nb)?bc[b4+1]:0;
  int v2 = (b4+2<nb)?bc[b4+2]:0;
  int v3 = (b4+3<nb)?bc[b4+3]:0;
  int sum=v0+v1+v2+v3;
  s[t]=sum; __syncthreads();
  for(int o=1;o<1024;o<<=1){
    int x = (t>=o)? s[t-o] : 0;
    __syncthreads();
    s[t]+=x;
    __syncthreads();
  }
  int excl=s[t]-sum;
  if(b4+0<nb) bc[b4+0]=excl;
  if(b4+1<nb) bc[b4+1]=excl+v0;
  if(b4+2<nb) bc[b4+2]=excl+v0+v1;
  if(b4+3<nb) bc[b4+3]=excl+v0+v1+v2;
  if(t==1023) *total = s[1023];
}

__global__ __launch_bounds__(TPB) void k_emit0(const float* __restrict__ c0, int n,
                                               const int* __restrict__ bc, int* __restrict__ list){
  int i = blockIdx.x*TPB + threadIdx.x;
  bool a = (i<n) && (c0[i]>0.f);
  unsigned long long bl = __ballot(a);
  __shared__ int woff[TPB/64];
  __shared__ int wpre[TPB/64];
  int lane=threadIdx.x&63, wv=threadIdx.x>>6;
  if(lane==0) woff[wv]=__popcll(bl);
  __syncthreads();
  if(threadIdx.x==0){ int acc=0; for(int w=0;w<TPB/64;w++){ wpre[w]=acc; acc+=woff[w]; } }
  __syncthreads();
  if(a) list[bc[blockIdx.x] + wpre[wv] + __popcll(bl&((1ull<<lane)-1ull))] = i;
}

// mark parents in dedup grid g (int) + append unique parents to coarse list
__global__ __launch_bounds__(TPB) void k_markparent_compact(const int* __restrict__ listF, const int* __restrict__ cntF,
        int ldf, int* __restrict__ g, int* __restrict__ listC, int* __restrict__ cntC){
  int i = blockIdx.x*TPB + threadIdx.x;
  bool first=false; int p=0;
  if(i < *cntF){
    int v=listF[i];
    int dm=(1<<ldf)-1;
    int x=v&dm, y=(v>>ldf)&dm, z=(v>>(2*ldf))&dm, b=v>>(3*ldf);
    p=vox(b,z>>1,y>>1,x>>1,ldf-1);
    first = (atomicExch(&g[p],1)==0);
  }
  append_list(first,p,listC,cntC);
}

// sparsify: keep sites with ch0 > 0; zero dropped in BOTH buffers + clear mask grid; compact keepers
__global__ __launch_bounds__(TPB) void k_sparsify_compact(float* __restrict__ X, float* __restrict__ Y,
        const int* __restrict__ listA, const int* __restrict__ cntA,
        int* __restrict__ listB, int* __restrict__ cntB, int* __restrict__ gmask){
  int i = blockIdx.x*TPB + threadIdx.x;
  bool keep=false; int v=0;
  if(i < *cntA){
    v = listA[i];
    keep = X[(size_t)v<<4] > 0.f;
    if(!keep){
      float4 zz = make_float4(0,0,0,0);
      float4* px=(float4*)(X+((size_t)v<<4)); px[0]=zz;px[1]=zz;px[2]=zz;px[3]=zz;
      float4* py=(float4*)(Y+((size_t)v<<4)); py[0]=zz;py[1]=zz;py[2]=zz;py[3]=zz;
      if(gmask) gmask[v]=0;
    }
  }
  append_list(keep,v,listB,cntB);
}

// prepare: 1 -> 16 ch, k=3 SAME, over active list; fused output stats
__global__ __launch_bounds__(TPB) void k_prep_l(const float* __restrict__ c0, const int* __restrict__ list,
          const int* __restrict__ cnt, const float* __restrict__ w, float* __restrict__ X,
          float* __restrict__ gsums){
  __shared__ float wl[432];
  __shared__ float red[(TPB/64)*32];
  for(int i=threadIdx.x;i<432;i+=TPB) wl[i]=w[i];
  __syncthreads();
  int i = blockIdx.x*TPB + threadIdx.x;
  bool act = i < *cnt;
  float4 a0=make_float4(0,0,0,0), a1=a0, a2=a0, a3=a0;
  if(act){
    int v=list[i];
    int x=v&63, y=(v>>6)&63, z=(v>>12)&63, b=v>>18;
    for(int dz=0;dz<3;dz++){ int zz=z+dz-1; if((unsigned)zz>=64u) continue;
      for(int dy=0;dy<3;dy++){ int yy=y+dy-1; if((unsigned)yy>=64u) continue;
        for(int dx=0;dx<3;dx++){ int xx=x+dx-1; if((unsigned)xx>=64u) continue;
          float av = c0[vox(b,zz,yy,xx,6)];
          if(av==0.f) continue;
          const float4* wv=(const float4*)&wl[((dz*3+dy)*3+dx)<<4];
          fma4(a0,av,wv[0]); fma4(a1,av,wv[1]); fma4(a2,av,wv[2]); fma4(a3,av,wv[3]);
        }
      }
    }
    float4* o=(float4*)(X+((size_t)v<<4));
    o[0]=a0;o[1]=a1;o[2]=a2;o[3]=a3;
  }
  stats_reduce(a0,a1,a2,a3,red,gsums);
}

// 16->16 k=3 SAME conv over active list
__global__ __launch_bounds__(CTPB) void k_conv3_l(const float* __restrict__ Xin, const int* __restrict__ list,
      const int* __restrict__ cnt, const float* __restrict__ w, float* __restrict__ Xout, int ld){
  __shared__ float wl[6912];
  for(int i=threadIdx.x;i<6912;i+=CTPB) wl[i]=w[i];
  __syncthreads();
  int i = blockIdx.x*CTPB + threadIdx.x;
  if(i >= *cnt) return;
  int v = list[i];
  int d=1<<ld, dm=d-1;
  int x=v&dm, y=(v>>ld)&dm, z=(v>>(2*ld))&dm, b=v>>(3*ld);
  float4 a0=make_float4(0,0,0,0), a1=a0, a2=a0, a3=a0;
  for(int dz=0;dz<3;dz++){ int zz=z+dz-1; if((unsigned)zz>=(unsigned)d) continue;
    for(int dy=0;dy<3;dy++){ int yy=y+dy-1; if((unsigned)yy>=(unsigned)d) continue;
      const float* srow = Xin + ((size_t)vox(b,zz,yy,0,ld)<<4);
      const float* wrow = &wl[((dz*3+dy)*3)<<8];
      for(int dx=0;dx<3;dx++){ int xx=x+dx-1; if((unsigned)xx>=(unsigned)d) continue;
        const float4* sp=(const float4*)(srow + ((size_t)xx<<4));
        float s[16];
        *(float4*)&s[0]=sp[0]; *(float4*)&s[4]=sp[1]; *(float4*)&s[8]=sp[2]; *(float4*)&s[12]=sp[3];
        const float* wt = wrow + (dx<<8);
        #pragma unroll
        for(int ci=0;ci<16;ci++){
          float av=s[ci];
          const float4* wv=(const float4*)(wt + (ci<<4));
          fma4(a0,av,wv[0]); fma4(a1,av,wv[1]); fma4(a2,av,wv[2]); fma4(a3,av,wv[3]);
        }
      }
    }
  }
  float4* o=(float4*)(Xout + ((size_t)v<<4));
  o[0]=a0;o[1]=a1;o[2]=a2;o[3]=a3;
}

// k=4 pad(1,2) conv over active list; fused output stats (LDS reused for reduction)
__global__ __launch_bounds__(CTPB) void k_conv4_l(const float* __restrict__ Xin, const int* __restrict__ list,
      const int* __restrict__ cnt, const float* __restrict__ w, float* __restrict__ Xout, int ld,
      float* __restrict__ gsums){
  extern __shared__ float wl4[];
  for(int i=threadIdx.x;i<16384;i+=CTPB) wl4[i]=w[i];
  __syncthreads();
  int i = blockIdx.x*CTPB + threadIdx.x;
  bool act = i < *cnt;
  float4 a0=make_float4(0,0,0,0), a1=a0, a2=a0, a3=a0;
  if(act){
    int v = list[i];
    int d=1<<ld, dm=d-1;
    int x=v&dm, y=(v>>ld)&dm, z=(v>>(2*ld))&dm, b=v>>(3*ld);
    for(int dz=0;dz<4;dz++){ int zz=z+dz-1; if((unsigned)zz>=(unsigned)d) continue;
      for(int dy=0;dy<4;dy++){ int yy=y+dy-1; if((unsigned)yy>=(unsigned)d) continue;
        const float* srow = Xin + ((size_t)vox(b,zz,yy,0,ld)<<4);
        const float* wrow = &wl4[((dz*4+dy))<<10];
        for(int dx=0;dx<4;dx++){ int xx=x+dx-1; if((unsigned)xx>=(unsigned)d) continue;
          const float4* sp=(const float4*)(srow + ((size_t)xx<<4));
          float s[16];
          *(float4*)&s[0]=sp[0]; *(float4*)&s[4]=sp[1]; *(float4*)&s[8]=sp[2]; *(float4*)&s[12]=sp[3];
          const float* wt = wrow + (dx<<8);
          #pragma unroll
          for(int ci=0;ci<16;ci++){
            float av=s[ci];
            const float4* wv=(const float4*)(wt + (ci<<4));
            fma4(a0,av,wv[0]); fma4(a1,av,wv[1]); fma4(a2,av,wv[2]); fma4(a3,av,wv[3]);
          }
        }
      }
    }
    float4* o=(float4*)(Xout + ((size_t)v<<4));
    o[0]=a0;o[1]=a1;o[2]=a2;o[3]=a3;
  }
  __syncthreads();                       // all weight reads done -> reuse wl4 for reduction
  stats_reduce(a0,a1,a2,a3,wl4,gsums);
}

// strided k=2 s=2 VALID down-conv over coarse list; fused output stats
__global__ __launch_bounds__(TPB) void k_down_l(const float* __restrict__ Xin, const int* __restrict__ list,
      const int* __restrict__ cnt, const float* __restrict__ w, float* __restrict__ Xout, int ldc,
      float* __restrict__ gsums){
  __shared__ float wl[2048];
  __shared__ float red[(TPB/64)*32];
  for(int i=threadIdx.x;i<2048;i+=TPB) wl[i]=w[i];
  __syncthreads();
  int i = blockIdx.x*TPB + threadIdx.x;
  bool act = i < *cnt;
  float4 a0=make_float4(0,0,0,0), a1=a0, a2=a0, a3=a0;
  if(act){
    int v = list[i];
    int dm=(1<<ldc)-1, ldf=ldc+1;
    int x=v&dm, y=(v>>ldc)&dm, z=(v>>(2*ldc))&dm, b=v>>(3*ldc);
    for(int dz=0;dz<2;dz++) for(int dy=0;dy<2;dy++) for(int dx=0;dx<2;dx++){
      const float4* sp=(const float4*)(Xin + ((size_t)vox(b,2*z+dz,2*y+dy,2*x+dx,ldf)<<4));
      float s[16];
      *(float4*)&s[0]=sp[0]; *(float4*)&s[4]=sp[1]; *(float4*)&s[8]=sp[2]; *(float4*)&s[12]=sp[3];
      const float* wt=&wl[(((dz<<1)|dy)<<1 | dx)<<8];
      #pragma unroll
      for(int ci=0;ci<16;ci++){
        float av=s[ci];
        const float4* wv=(const float4*)(wt+(ci<<4));
        fma4(a0,av,wv[0]); fma4(a1,av,wv[1]); fma4(a2,av,wv[2]); fma4(a3,av,wv[3]);
      }
    }
    float4* o=(float4*)(Xout+((size_t)v<<4));
    o[0]=a0;o[1]=a1;o[2]=a2;o[3]=a3;
  }
  stats_reduce(a0,a1,a2,a3,red,gsums);
}

// conv_transpose k=2 s=2 with BN+ReLU folded onto the coarse operand.
// gmask distinguishes truly-active coarse sites (BN applies) from sparsified-away (contribute 0).
__global__ __launch_bounds__(TPB) void k_upbn_l(const float* __restrict__ Xc, const int* __restrict__ list,
      const int* __restrict__ cnt, const float* __restrict__ w,
      const float* __restrict__ sums, const int* __restrict__ bncnt,
      const float* __restrict__ g, const float* __restrict__ bta,
      const int* __restrict__ gmask, float* __restrict__ Xf, int ldf){
  __shared__ float wl[2048];
  __shared__ float sc[16], sh[16];
  for(int i=threadIdx.x;i<2048;i+=TPB) wl[i]=w[i];
  if(threadIdx.x<16){
    int c=threadIdx.x;
    float n=(float)(*bncnt); if(n<1.f) n=1.f;
    float mean=sums[c]/n;
    float var=sums[16+c]/n - mean*mean;
    float s=g[c]/sqrtf(var+1e-4f);
    sc[c]=s; sh[c]=fmaf(-mean,s,bta[c]);
  }
  __syncthreads();
  int i = blockIdx.x*TPB + threadIdx.x;
  if(i >= *cnt) return;
  int v = list[i];
  int dm=(1<<ldf)-1, ldc=ldf-1;
  int x=v&dm, y=(v>>ldf)&dm, z=(v>>(2*ldf))&dm, b=v>>(3*ldf);
  int p = vox(b,z>>1,y>>1,x>>1,ldc);
  float4 a0=make_float4(0,0,0,0), a1=a0, a2=a0, a3=a0;
  if(gmask[p]!=0){
    const float4* sp=(const float4*)(Xc + ((size_t)p<<4));
    float s[16];
    *(float4*)&s[0]=sp[0]; *(float4*)&s[4]=sp[1]; *(float4*)&s[8]=sp[2]; *(float4*)&s[12]=sp[3];
    #pragma unroll
    for(int ci=0;ci<16;ci++){ float xh=fmaf(s[ci],sc[ci],sh[ci]); s[ci]=xh>0.f?xh:0.f; }
    int t = ((((z&1)^1)<<1 | ((y&1)^1))<<1) | ((x&1)^1);
    const float* wt=&wl[t<<8];
    #pragma unroll
    for(int ci=0;ci<16;ci++){
      float av=s[ci];
      const float4* wv=(const float4*)(wt+(ci<<4));
      fma4(a0,av,wv[0]); fma4(a1,av,wv[1]); fma4(a2,av,wv[2]); fma4(a3,av,wv[3]);
    }
  }
  float4* o=(float4*)(Xf+((size_t)v<<4));
  o[0]=a0;o[1]=a1;o[2]=a2;o[3]=a3;
}

// encoder BN finalize + apply (ReLU) over active list, in place
__global__ __launch_bounds__(TPB) void k_bnapply(float* __restrict__ X, const int* __restrict__ list,
        const int* __restrict__ cnt, const float* __restrict__ sums,
        const float* __restrict__ g, const float* __restrict__ bta){
  __shared__ float sc[16], sh[16];
  if(threadIdx.x<16){
    int c=threadIdx.x;
    float n=(float)(*cnt); if(n<1.f) n=1.f;
    float mean=sums[c]/n;
    float var=sums[16+c]/n - mean*mean;
    float s=g[c]/sqrtf(var+1e-4f);
    sc[c]=s; sh[c]=fmaf(-mean,s,bta[c]);
  }
  __syncthreads();
  int i = blockIdx.x*TPB + threadIdx.x;
  if(i>=*cnt) return;
  float* p = X + ((size_t)list[i]<<4);
  #pragma unroll
  for(int c=0;c<16;c++){
    float xh = fmaf(p[c], sc[c], sh[c]);
    p[c] = xh>0.f ? xh : 0.f;
  }
}

// hidden = NCDHW flatten of level-3 features
__global__ __launch_bounds__(TPB) void k_hidden(const float* __restrict__ X3, float* __restrict__ out){
  int i = blockIdx.x*TPB + threadIdx.x;
  if(i>=4*8192) return;
  int b=i>>13, r=i&8191, c=r>>9, s=r&511;
  out[i] = X3[(((size_t)((b<<9)|s))<<4)|c];
}

// output conv 16 -> 1, k=3 SAME, over active list
__global__ __launch_bounds__(TPB) void k_final_l(const float* __restrict__ Xin, const int* __restrict__ list,
      const int* __restrict__ cnt, const float* __restrict__ w, float* __restrict__ out){
  __shared__ float wl[432];
  for(int i=threadIdx.x;i<432;i+=TPB) wl[i]=w[i];
  __syncthreads();
  int i = blockIdx.x*TPB + threadIdx.x;
  if(i >= *cnt) return;
  int v = list[i];
  float acc=0.f;
  int x=v&63, y=(v>>6)&63, z=(v>>12)&63, b=v>>18;
  for(int dz=0;dz<3;dz++){ int zz=z+dz-1; if((unsigned)zz>=64u) continue;
    for(int dy=0;dy<3;dy++){ int yy=y+dy-1; if((unsigned)yy>=64u) continue;
      for(int dx=0;dx<3;dx++){ int xx=x+dx-1; if((unsigned)xx>=64u) continue;
        const float* sp = Xin + ((size_t)vox(b,zz,yy,xx,6)<<4);
        const float* wt = &wl[((dz*3+dy)*3+dx)<<4];
        #pragma unroll
        for(int ci=0;ci<16;ci++) acc = fmaf(sp[ci], wt[ci], acc);
      }
    }
  }
  out[v]=acc;
}

static inline int nb(int n){ return (n+TPB-1)/TPB; }
static inline int nbC(int n){ return (n+CTPB-1)/CTPB; }
static inline size_t rbytes(int ld){ return ((size_t)4<<(3*ld))*64; }

extern "C" void kernel_launch(void* const* d_in, const int* in_sizes, int n_in,
                              void* d_out, int out_size, void* d_ws, size_t ws_size,
                              hipStream_t stream){
  const float* data   = (const float*)d_in[0];
  const int*   cl     = (const int*)d_in[1];
  const float* w_prep = (const float*)d_in[2];
  const float* enc_g  = (const float*)d_in[3];
  const float* enc_b  = (const float*)d_in[4];
  const float* enc_ws = (const float*)d_in[5];
  const float* enc_wd = (const float*)d_in[6];
  const float* dec_g  = (const float*)d_in[7];
  const float* dec_b  = (const float*)d_in[8];
  const float* dec_wu = (const float*)d_in[9];
  const float* dec_w3 = (const float*)d_in[10];
  const float* dec_w4 = (const float*)d_in[11];
  const float* w_out  = (const float*)d_in[12];
  int N = in_sizes[0]/5;
  float* outp = (float*)d_out;

  const size_t FEAT_ROOMY = 38305792;   // A0,B0,A1,B1,A2,B2,A3 (floats)
  const size_t FEAT_TIGHT = 33554432;   // X,Y
  const size_t TAILN      = 1048576 + 149504 + 224 + 16 + 4096 + 821248;
  bool roomy = ws_size >= (FEAT_ROOMY + TAILN)*sizeof(float);

  float* ws = (float*)d_ws;
  float *A[4]={0,0,0,0}, *B[4]={0,0,0,0}, *X=0, *Y=0;
  size_t featsz;
  if(roomy){
    A[0]=ws;            B[0]=A[0]+16777216;
    A[1]=B[0]+16777216; B[1]=A[1]+2097152;
    A[2]=B[1]+2097152;  B[2]=A[2]+262144;
    A[3]=B[2]+262144;
    featsz=FEAT_ROOMY;
  } else { X=ws; Y=X+16777216; featsz=FEAT_TIGHT; }
  float* c0 = ws + featsz;
  int* g1=(int*)(c0+1048576); int* g2=g1+131072; int* g3=g2+16384;
  float* sums=(float*)(g3+2048);
  int* counts=(int*)(sums+224);
  int* bc=counts+16;
  int* l0a=bc+4096; int* l0b=l0a+262144; int* l1a=l0b+262144; int* l1b=l1a+131072;
  int* l2a=l1b+131072; int* l2b=l2a+16384; int* l3=l2b+16384;
  int* la[4]={l0a,l1a,l2a,l3};
  int* lb[3]={l0b,l1b,l2b};
  int* g[4]={nullptr,g1,g2,g3};
  int b0 = N<262144?N:262144;
  int bounds[4]={b0,131072,16384,2048};

  // zero features + (c0, grids, sums, counts, bc) in two memsets
  hipMemsetAsync(ws, 0, featsz*sizeof(float), stream);
  hipMemsetAsync(c0, 0, (1048576+149504+224+16+4096)*sizeof(float), stream);

  k_scatter<<<nb(N),TPB,0,stream>>>(data, cl, N, c0);
  k_cnt0 <<<4096,TPB,0,stream>>>(c0, 1048576, bc);
  k_scan0<<<1,1024,0,stream>>>(bc, 4096, counts+0);
  k_emit0<<<4096,TPB,0,stream>>>(c0, 1048576, bc, l0a);

  if(roomy){
    k_prep_l<<<nb(b0),TPB,0,stream>>>(c0, l0a, counts+0, w_prep, A[0], sums);
    for(int i=0;i<3;i++){
      int ld=6-i;
      k_bnapply<<<nb(bounds[i]),TPB,0,stream>>>(A[i], la[i], counts+i, sums+32*i, enc_g+16*i, enc_b+16*i);
      k_conv3_l<<<nbC(bounds[i]),CTPB,0,stream>>>(A[i], la[i], counts+i, enc_ws+6912*i, B[i], ld);
      k_markparent_compact<<<nb(bounds[i]),TPB,0,stream>>>(la[i], counts+i, ld, g[i+1], la[i+1], counts+(i+1));
      k_down_l<<<nb(bounds[i+1]),TPB,0,stream>>>(B[i], la[i+1], counts+(i+1), enc_wd+2048*i, A[i+1], ld-1, sums+32*(i+1));
    }
    k_hidden<<<nb(32768),TPB,0,stream>>>(A[3], outp);
    for(int j=0;j<3;j++){
      int lvl=2-j, ldf=6-lvl;
      const int* bncnt = (j==0)? counts+3 : counts+4+(lvl+1);
      k_upbn_l<<<nb(bounds[lvl]),TPB,0,stream>>>(A[lvl+1], la[lvl], counts+lvl, dec_wu+2048*j,
            sums+32*(3+j), bncnt, dec_g+16*j, dec_b+16*j, g[lvl+1], A[lvl], ldf);
      k_conv3_l<<<nbC(bounds[lvl]),CTPB,0,stream>>>(A[lvl], la[lvl], counts+lvl, dec_w3+6912*j, B[lvl], ldf);
      k_sparsify_compact<<<nb(bounds[lvl]),TPB,0,stream>>>(B[lvl], A[lvl], la[lvl], counts+lvl, lb[lvl], counts+4+lvl, g[lvl]);
      float* ss = (j<2)? sums+32*(4+j) : sums+32*6;
      k_conv4_l<<<nbC(bounds[lvl]),CTPB,65536,stream>>>(B[lvl], lb[lvl], counts+4+lvl, dec_w4+16384*j, A[lvl], ldf, ss);
    }
    hipMemsetAsync(outp+32768, 0, (size_t)1048576*sizeof(float), stream);
    k_final_l<<<nb(b0),TPB,0,stream>>>(A[0], lb[0], counts+4, w_out, outp+32768);
  } else {
    k_prep_l<<<nb(b0),TPB,0,stream>>>(c0, l0a, counts+0, w_prep, X, sums);
    float* cur=X; float* oth=Y; int ld=6;
    for(int i=0;i<3;i++){
      k_bnapply<<<nb(bounds[i]),TPB,0,stream>>>(cur, la[i], counts+i, sums+32*i, enc_g+16*i, enc_b+16*i);
      hipMemsetAsync(oth, 0, rbytes(ld), stream);
      k_conv3_l<<<nbC(bounds[i]),CTPB,0,stream>>>(cur, la[i], counts+i, enc_ws+6912*i, oth, ld);
      { float* t=cur; cur=oth; oth=t; }
      k_markparent_compact<<<nb(bounds[i]),TPB,0,stream>>>(la[i], counts+i, ld, g[i+1], la[i+1], counts+(i+1));
      hipMemsetAsync(oth, 0, rbytes(ld-1), stream);
      k_down_l<<<nb(bounds[i+1]),TPB,0,stream>>>(cur, la[i+1], counts+(i+1), enc_wd+2048*i, oth, ld-1, sums+32*(i+1));
      { float* t=cur; cur=oth; oth=t; }
      ld--;
    }
    k_hidden<<<nb(32768),TPB,0,stream>>>(cur, outp);
    for(int j=0;j<3;j++){
      int lvl=2-j, ldf=ld+1;
      const int* bncnt = (j==0)? counts+3 : counts+4+(lvl+1);
      hipMemsetAsync(oth, 0, rbytes(ldf), stream);
      k_upbn_l<<<nb(bounds[lvl]),TPB,0,stream>>>(cur, la[lvl], counts+lvl, dec_wu+2048*j,
            sums+32*(3+j), bncnt, dec_g+16*j, dec_b+16*j, g[lvl+1], oth, ldf);
      { float* t=cur; cur=oth; oth=t; }
      hipMemsetAsync(oth, 0, rbytes(ldf), stream);
      k_conv3_l<<<nbC(bounds[lvl]),CTPB,0,stream>>>(cur, la[lvl], counts+lvl, dec_w3+6912*j, oth, ldf);
      { float* t=cur; cur=oth; oth=t; }
      k_sparsify_compact<<<nb(bounds[lvl]),TPB,0,stream>>>(cur, oth, la[lvl], counts+lvl, lb[lvl], counts+4+lvl, g[lvl]);
      float* ss = (j<2)? sums+32*(4+j) : sums+32*6;
      k_conv4_l<<<nbC(bounds[lvl]),CTPB,65536,stream>>>(cur, lb[lvl], counts+4+lvl, dec_w4+16384*j, oth, ldf, ss);
      { float* t=cur; cur=oth; oth=t; }
      ld=ldf;
    }
    hipMemsetAsync(outp+32768, 0, (size_t)1048576*sizeof(float), stream);
    k_final_l<<<nb(b0),TPB,0,stream>>>(cur, lb[0], counts+4, w_out, outp+32768);
  }
}